// Round 7
// baseline (205.387 us; speedup 1.0000x reference)
//
#include <hip/hip_runtime.h>
#include <cstdint>

typedef unsigned short ushortT;
typedef __attribute__((ext_vector_type(8))) short short8;      // 8 bf16 = 4 VGPRs (MFMA A/B frag)
typedef __attribute__((ext_vector_type(8))) unsigned short ushort8v;
typedef __attribute__((ext_vector_type(4))) float float4v;

#define ATT_SCALE 0.17677669529663687f   // 32^-0.5

__device__ inline float bf2f(unsigned short u) {
    union { unsigned int i; float f; } x; x.i = ((unsigned int)u) << 16; return x.f;
}
__device__ inline unsigned short f2bf(float f) {
    union { float f; unsigned int i; } x; x.f = f;
    unsigned int i = x.i;
    i += 0x7fffu + ((i >> 16) & 1u);      // RNE
    return (unsigned short)(i >> 16);
}

// ---------------------------------------------------------------------------
// Convert params (fp32 in): weights -> bf16, biases -> fp32 copy.
// ---------------------------------------------------------------------------
__global__ __launch_bounds__(256) void convert_params(const float* __restrict__ w_qkv,
                                                      const float* __restrict__ w_proj,
                                                      const float* __restrict__ b_qkv,
                                                      const float* __restrict__ b_proj,
                                                      ushortT* __restrict__ wqkvB,
                                                      ushortT* __restrict__ wprojB,
                                                      float* __restrict__ bqF,
                                                      float* __restrict__ bpF) {
    int i = blockIdx.x * 256 + threadIdx.x;
    if (i < 196608) {
        wqkvB[i] = f2bf(w_qkv[i]);
    } else if (i < 262144) {
        wprojB[i - 196608] = f2bf(w_proj[i - 196608]);
    } else if (i < 262912) {
        bqF[i - 262144] = b_qkv[i - 262144];
    } else if (i < 263168) {
        bpF[i - 262912] = b_proj[i - 262912];
    }
}

// ---------------------------------------------------------------------------
// Transpose+convert (B, 256, 4096) fp32 -> (B, 4096, 256) bf16.
// grid (C/64=4, P/64=64, B=8), block 256. Destination lives in d_out (dead
// until the final projection GEMM overwrites every element).
// ---------------------------------------------------------------------------
__global__ __launch_bounds__(256) void transpose_cp(const float* __restrict__ x,
                                                    ushortT* __restrict__ xT) {
    __shared__ __align__(16) ushortT tile[64][65];
    const int b  = blockIdx.z;
    const int c0 = blockIdx.x * 64;
    const int p0 = blockIdx.y * 64;
    const int t  = threadIdx.x;

    const float* xb = x + (size_t)b * 256 * 4096;
#pragma unroll
    for (int it = 0; it < 4; it++) {
        int id  = t + it * 256;          // 0..1023
        int row = id >> 4;               // c row 0..63
        int c4  = (id & 15) * 4;         // p chunk of 4 floats
        float4 v = *(const float4*)(xb + (size_t)(c0 + row) * 4096 + p0 + c4);
        tile[row][c4 + 0] = f2bf(v.x);
        tile[row][c4 + 1] = f2bf(v.y);
        tile[row][c4 + 2] = f2bf(v.z);
        tile[row][c4 + 3] = f2bf(v.w);
    }
    __syncthreads();
    ushortT* xTb = xT + (size_t)b * 4096 * 256;
#pragma unroll
    for (int it = 0; it < 2; it++) {
        int id   = t + it * 256;             // 0..511
        int prow = id >> 3;                  // p row 0..63
        int cc   = (id & 7) * 8;             // c chunk
        ushort8v v;
#pragma unroll
        for (int j = 0; j < 8; j++) v[j] = tile[cc + j][prow];
        *(ushort8v*)(xTb + (size_t)(p0 + prow) * 256 + c0 + cc) = v;
    }
}

// ---------------------------------------------------------------------------
// LDS-free direct-register GEMM.  D[m][n] = sum_k A[m][k]*Bt[n][k] + bias.
// K hardcoded 256 (8 kt-iters, fully unrolled). Each wave loads its MFMA
// fragments straight from global (16B/lane; 16 rows x 64B contiguous segments
// per frag-load) -> NO K-loop barriers, no convoy; compiler pipelines loads
// against MFMAs per-wave with plain vmcnt scheduling. B operands (weights /
// y-slices) are L2-resident, A rows are L1-reused across kt.
// B: bHeadMajor -> Bt[((k>>5)*32768 + n)*32 + (k&31)], else row-major ldb.
// D: dHeadMajor -> bf16 head-major via LDS restage (coalesced 16B stores);
//    else row-major ldd, fp32 if outF32 else bf16.
// 128x128 block tile, 4 waves x (64x64 quadrant, 4x4 frags).
// grid: (N/128, M/128, batches); Bt/D batch-strided (elements).
// ---------------------------------------------------------------------------
__global__ __launch_bounds__(256) void gemm_direct(const ushortT* __restrict__ A,
                                                   const ushortT* __restrict__ Bt, long long sBb,
                                                   int ldb, int bHeadMajor,
                                                   void* __restrict__ D, long long sDb,
                                                   int ldd, int dHeadMajor, int outF32,
                                                   const float* __restrict__ bias, int biasAlongM,
                                                   int K) {
    __shared__ __align__(16) ushortT pool[16384];   // 32 KB, epilogue restage only

    const int bz = blockIdx.z;
    Bt += (size_t)bz * sBb;

    const int n0   = blockIdx.x * 128;
    const int m0   = blockIdx.y * 128;
    const int t    = threadIdx.x;
    const int wv   = t >> 6;
    const int lane = t & 63;
    const int lm   = lane & 15;
    const int quad = lane >> 4;
    const int wm   = wv & 1;     // wave's 64-row quadrant (m)
    const int wn   = wv >> 1;    // wave's 64-col quadrant (n)

    float4v acc[4][4];
#pragma unroll
    for (int i = 0; i < 4; i++)
#pragma unroll
        for (int j = 0; j < 4; j++) { float4v z = {0.f, 0.f, 0.f, 0.f}; acc[i][j] = z; }

    // Per-frag base addresses (row part is kt-invariant)
    const ushortT* aBase[4];
#pragma unroll
    for (int i = 0; i < 4; i++)
        aBase[i] = A + (size_t)(m0 + wm * 64 + i * 16 + lm) * K + quad * 8;
    const ushortT* bBase[4];
#pragma unroll
    for (int j = 0; j < 4; j++) {
        int n = n0 + wn * 64 + j * 16 + lm;
        bBase[j] = bHeadMajor ? Bt + (size_t)n * 32 + quad * 8
                              : Bt + (size_t)n * ldb + quad * 8;
    }
    const size_t bStep = bHeadMajor ? (size_t)32768 * 32 : 32;   // per-kt element step

#pragma unroll
    for (int kt = 0; kt < 8; ++kt) {
        short8 af[4], bfr[4];
#pragma unroll
        for (int i = 0; i < 4; i++)
            af[i] = *(const short8*)(aBase[i] + kt * 32);
#pragma unroll
        for (int j = 0; j < 4; j++)
            bfr[j] = *(const short8*)(bBase[j] + (size_t)kt * bStep);
#pragma unroll
        for (int i = 0; i < 4; i++)
#pragma unroll
            for (int j = 0; j < 4; j++)
                acc[i][j] = __builtin_amdgcn_mfma_f32_16x16x32_bf16(af[i], bfr[j], acc[i][j], 0, 0, 0);
    }

    // epilogue: C/D layout col = lane&15, row = quad*4 + reg
    if (dHeadMajor) {
        // Stage 128x128 bf16 tile in LDS (chunk-XOR swizzle on (r&7)), then
        // write 4 groups x 8KB fully-contiguous with ushort8 stores.
#pragma unroll
        for (int i = 0; i < 4; i++) {
#pragma unroll
            for (int j = 0; j < 4; j++) {
                int c = wn * 64 + j * 16 + lm;
#pragma unroll
                for (int rg = 0; rg < 4; rg++) {
                    int r = wm * 64 + i * 16 + quad * 4 + rg;
                    float v = acc[i][j][rg] + bias[biasAlongM ? (m0 + r) : (n0 + c)];
                    int chunk = (c >> 3) ^ (r & 7);
                    pool[r * 128 + chunk * 8 + (c & 7)] = f2bf(v);
                }
            }
        }
        __syncthreads();
        ushortT* Dh = (ushortT*)D + (size_t)bz * sDb;
#pragma unroll
        for (int g = 0; g < 4; g++) {
            ushortT* base = Dh + ((size_t)((n0 >> 5) + g) * 32768 + m0) * 32;
#pragma unroll
            for (int it = 0; it < 2; it++) {
                int id = it * 256 + t;          // 0..511
                int r  = id >> 2;
                int cb = id & 3;                // 8-chunk within group
                int pch = (g * 4 + cb) ^ (r & 7);
                ushort8v v = *(const ushort8v*)&pool[r * 128 + pch * 8];
                *(ushort8v*)(base + r * 32 + cb * 8) = v;
            }
        }
    } else {
        float*   Df = (float*)D   + (size_t)bz * sDb;
        ushortT* Dh = (ushortT*)D + (size_t)bz * sDb;
#pragma unroll
        for (int i = 0; i < 4; i++) {
            int r0 = m0 + wm * 64 + i * 16 + quad * 4;
#pragma unroll
            for (int j = 0; j < 4; j++) {
                int c = n0 + wn * 64 + j * 16 + lm;
#pragma unroll
                for (int rg = 0; rg < 4; rg++) {
                    int r = r0 + rg;
                    float v = acc[i][j][rg] + bias[biasAlongM ? r : c];
                    if (outF32) Df[(size_t)r * ldd + c] = v;
                    else        Dh[(size_t)r * ldd + c] = f2bf(v);
                }
            }
        }
    }
}

// ---------------------------------------------------------------------------
// Multi-dilated 3x3 local attention, IN-PLACE on HEAD-MAJOR bf16 qkv:
// qkv[(part*8+hd)*32768 + bp][32], part in {q,k,v}.
// One wave = 64 consecutive pixels (one image row) of ONE head -> all q/k/v
// loads are contiguous 4KB/wave segments; hh bounds are wave-uniform.
// Thread writes only its own q slice (k/v never written) -> race-free.
// ---------------------------------------------------------------------------
__global__ __launch_bounds__(256) void attn_k(ushortT* qkv) {
    const int gt   = blockIdx.x * 256 + threadIdx.x;
    const int lane = gt & 63;
    const int wid  = gt >> 6;          // 0..4095
    const int hd   = wid >> 9;         // 0..7  (512 waves per head)
    const int rowI = wid & 511;        // b*64 + h
    const int b    = rowI >> 6;
    const int h    = rowI & 63;
    const int w    = lane;
    const int dil  = (hd & 3) + 1;     // DILATIONS = [1,2,3,4]
    const int bp   = b * 4096 + h * 64 + w;

    ushortT*       qp    = qkv + ((size_t)hd * 32768 + bp) * 32;
    const ushortT* kbase = qkv + ((size_t)(8  + hd) * 32768 + (size_t)b * 4096) * 32;
    const ushortT* vbase = qkv + ((size_t)(16 + hd) * 32768 + (size_t)b * 4096) * 32;

    float q[32];
#pragma unroll
    for (int c = 0; c < 4; c++) {
        ushort8v v = *(const ushort8v*)(qp + c * 8);
#pragma unroll
        for (int j = 0; j < 8; j++) q[c * 8 + j] = bf2f(v[j]);
    }

    float lgt[9];
    int   nb[9];
    unsigned vmask = 0;
#pragma unroll
    for (int ii = 0; ii < 3; ii++) {
#pragma unroll
        for (int jj = 0; jj < 3; jj++) {
            int idx = ii * 3 + jj;
            int hh = h + (ii - 1) * dil;   // wave-uniform
            int ww = w + (jj - 1) * dil;
            bool ok = ((unsigned)hh < 64u) && ((unsigned)ww < 64u);
            int pp = (hh << 6) + ww;
            nb[idx] = pp;
            float l = 0.f;                 // OOB: k is zero-padded -> logit exactly 0
            if (ok) {
                vmask |= (1u << idx);
                const ushortT* kp = kbase + (size_t)pp * 32;
#pragma unroll
                for (int c = 0; c < 4; c++) {
                    ushort8v v = *(const ushort8v*)(kp + c * 8);
#pragma unroll
                    for (int j = 0; j < 8; j++) l += q[c * 8 + j] * bf2f(v[j]);
                }
                l *= ATT_SCALE;
            }
            lgt[idx] = l;
        }
    }

    float mx = lgt[0];
#pragma unroll
    for (int i = 1; i < 9; i++) mx = fmaxf(mx, lgt[i]);
    float e[9], s = 0.f;
#pragma unroll
    for (int i = 0; i < 9; i++) { e[i] = __expf(lgt[i] - mx); s += e[i]; }
    const float inv = 1.f / s;

    float acc[32];
#pragma unroll
    for (int d = 0; d < 32; d++) acc[d] = 0.f;
#pragma unroll
    for (int idx = 0; idx < 9; idx++) {
        if ((vmask >> idx) & 1u) {        // OOB: v = 0, contributes nothing (e[idx] stays in s)
            float pj = e[idx] * inv;
            const ushortT* vp = vbase + (size_t)nb[idx] * 32;
#pragma unroll
            for (int c = 0; c < 4; c++) {
                ushort8v v = *(const ushort8v*)(vp + c * 8);
#pragma unroll
                for (int j = 0; j < 8; j++) acc[c * 8 + j] += pj * bf2f(v[j]);
            }
        }
    }

#pragma unroll
    for (int c = 0; c < 4; c++) {         // overwrite own q slice
        ushort8v v;
#pragma unroll
        for (int j = 0; j < 8; j++) v[j] = f2bf(acc[c * 8 + j]);
        *(ushort8v*)(qp + c * 8) = v;
    }
}

// ---------------------------------------------------------------------------
extern "C" void kernel_launch(void* const* d_in, const int* in_sizes, int n_in,
                              void* d_out, int out_size, void* d_ws, size_t ws_size,
                              hipStream_t stream) {
    const float* x      = (const float*)d_in[0];  // (8,256,64,64) fp32
    const float* w_qkv  = (const float*)d_in[1];  // (768,256)
    const float* b_qkv  = (const float*)d_in[2];  // (768,)
    const float* w_proj = (const float*)d_in[3];  // (256,256)
    const float* b_proj = (const float*)d_in[4];  // (256,)

    // ws layout (256B-aligned): bqF | bpF | wqkvB | wprojB | qkv(head-major)
    char* ws = (char*)d_ws;
    float*   bqF    = (float*)(ws + 256);              // 768 f32
    float*   bpF    = (float*)(ws + 3328);             // 256 f32
    ushortT* wqkvB  = (ushortT*)(ws + 4352);           // 196608 bf16
    ushortT* wprojB = (ushortT*)(ws + 397568);         // 65536 bf16
    ushortT* qkv    = (ushortT*)(ws + 528640);         // 24 x 32768 x 32 bf16 = 48 MiB
    ushortT* xT     = (ushortT*)d_out;                 // (32768,256) bf16 scratch in d_out;
                                                       // fully overwritten by the final GEMM

    // 0) weights -> bf16, biases -> fp32
    convert_params<<<1028, 256, 0, stream>>>(w_qkv, w_proj, b_qkv, b_proj,
                                             wqkvB, wprojB, bqF, bpF);

    // 1) x (B,C,P) -> xT (B,P,C) bf16
    transpose_cp<<<dim3(4, 64, 8), 256, 0, stream>>>(x, xT);

    // 2) qkv head-major = xT(32768,256) @ w_qkv^T + b_qkv   (bias along n)
    gemm_direct<<<dim3(6, 256, 1), 256, 0, stream>>>(xT, wqkvB, 0, 256, 0,
                                                     qkv, 0, 0, 1, 0,
                                                     bqF, 0, 256);

    // 3) attention in-place on head-major qkv (y overwrites q slices)
    attn_k<<<dim3(1024), 256, 0, stream>>>(qkv);

    // 4) out(b,256,4096) fp32 = w_proj @ y(b)^T + b_proj  (bias along m)
    //    y = q-slices of head-major qkv; batch stride = 4096*32 elements
    gemm_direct<<<dim3(32, 2, 8), 256, 0, stream>>>(wprojB, qkv, (long long)4096 * 32, 0, 1,
                                                    d_out, (long long)256 * 4096, 4096, 0, 1,
                                                    bpF, 1, 256);
}

// Round 8
// 178.328 us; speedup vs baseline: 1.1517x; 1.1517x over previous
//
#include <hip/hip_runtime.h>
#include <cstdint>

typedef unsigned short ushortT;
typedef __attribute__((ext_vector_type(8))) short short8;      // 8 bf16 = 4 VGPRs (MFMA A/B frag)
typedef __attribute__((ext_vector_type(8))) unsigned short ushort8v;
typedef __attribute__((ext_vector_type(4))) float float4v;

#define ATT_SCALE 0.17677669529663687f   // 32^-0.5

__device__ inline float bf2f(unsigned short u) {
    union { unsigned int i; float f; } x; x.i = ((unsigned int)u) << 16; return x.f;
}
__device__ inline unsigned short f2bf(float f) {
    union { float f; unsigned int i; } x; x.f = f;
    unsigned int i = x.i;
    i += 0x7fffu + ((i >> 16) & 1u);      // RNE
    return (unsigned short)(i >> 16);
}

__device__ inline void gld_lds16(const ushortT* g, ushortT* l) {
    // async global->LDS, 16B/lane; LDS dest = wave-uniform base + lane*16
    __builtin_amdgcn_global_load_lds((const __attribute__((address_space(1))) void*)g,
                                     (__attribute__((address_space(3))) void*)l, 16, 0, 0);
}

// ---------------------------------------------------------------------------
// Convert params (fp32 in): weights -> bf16, biases -> fp32 copy.
// ---------------------------------------------------------------------------
__global__ __launch_bounds__(256) void convert_params(const float* __restrict__ w_qkv,
                                                      const float* __restrict__ w_proj,
                                                      const float* __restrict__ b_qkv,
                                                      const float* __restrict__ b_proj,
                                                      ushortT* __restrict__ wqkvB,
                                                      ushortT* __restrict__ wprojB,
                                                      float* __restrict__ bqF,
                                                      float* __restrict__ bpF) {
    int i = blockIdx.x * 256 + threadIdx.x;
    if (i < 196608) {
        wqkvB[i] = f2bf(w_qkv[i]);
    } else if (i < 262144) {
        wprojB[i - 196608] = f2bf(w_proj[i - 196608]);
    } else if (i < 262912) {
        bqF[i - 262144] = b_qkv[i - 262144];
    } else if (i < 263168) {
        bpF[i - 262912] = b_proj[i - 262912];
    }
}

// ---------------------------------------------------------------------------
// Transpose+convert (B, 256, 4096) fp32 -> (B, 4096, 256) bf16.
// grid (C/64=4, P/64=64, B=8), block 256. Destination lives in d_out (dead
// until the final projection GEMM overwrites every element).
// ---------------------------------------------------------------------------
__global__ __launch_bounds__(256) void transpose_cp(const float* __restrict__ x,
                                                    ushortT* __restrict__ xT) {
    __shared__ __align__(16) ushortT tile[64][65];
    const int b  = blockIdx.z;
    const int c0 = blockIdx.x * 64;
    const int p0 = blockIdx.y * 64;
    const int t  = threadIdx.x;

    const float* xb = x + (size_t)b * 256 * 4096;
#pragma unroll
    for (int it = 0; it < 4; it++) {
        int id  = t + it * 256;          // 0..1023
        int row = id >> 4;               // c row 0..63
        int c4  = (id & 15) * 4;         // p chunk of 4 floats
        float4 v = *(const float4*)(xb + (size_t)(c0 + row) * 4096 + p0 + c4);
        tile[row][c4 + 0] = f2bf(v.x);
        tile[row][c4 + 1] = f2bf(v.y);
        tile[row][c4 + 2] = f2bf(v.z);
        tile[row][c4 + 3] = f2bf(v.w);
    }
    __syncthreads();
    ushortT* xTb = xT + (size_t)b * 4096 * 256;
#pragma unroll
    for (int it = 0; it < 2; it++) {
        int id   = t + it * 256;             // 0..511
        int prow = id >> 3;                  // p row 0..63
        int cc   = (id & 7) * 8;             // c chunk
        ushort8v v;
#pragma unroll
        for (int j = 0; j < 8; j++) v[j] = tile[cc + j][prow];
        *(ushort8v*)(xTb + (size_t)(p0 + prow) * 256 + c0 + cc) = v;
    }
}

// ---------------------------------------------------------------------------
// GEMM  D[m][n] = sum_k A[m][k] * Bt[n][k]  + bias   (bf16 in, fp32 acc)
// R5 structure (best measured): 2-barrier staged K-loop, global_load_lds w=16,
// XOR-chunk LDS swizzle, LDS-restaged head-major epilogue.
// NEW: XCD-aware 1-D block swizzle — blocks sharing a tile land on the SAME
// XCD (id%8) so the shared tile is fetched into one per-XCD L2 once:
//   swizzleMode 0 (qkv, 1536 blocks): r=id&7, j=id>>3; m-tile = r*32 + j/6
//       (6 n-blocks sharing an A-tile are consecutive j -> same r); n = j%6; bz=0.
//   swizzleMode 1 (proj, 512 blocks): r=id&7, j=id>>3; p = r*32 + (j>>1);
//       bz = p>>5, n-tile = p&31, m-tile = j&1 (2 m-blocks sharing a y-tile
//       are consecutive j -> same r).
// B: bHeadMajor -> Bt[((k>>5)*32768 + n)*32 + (k&31)], else row-major ldb.
// D: dHeadMajor -> bf16 head-major via LDS restage; else row-major ldd,
//    fp32 if outF32 else bf16.
// ---------------------------------------------------------------------------
__global__ __launch_bounds__(256) void gemm_bt(const ushortT* __restrict__ A,
                                               const ushortT* __restrict__ Bt, long long sBb,
                                               int ldb, int bHeadMajor,
                                               void* __restrict__ D, long long sDb,
                                               int ldd, int dHeadMajor, int outF32,
                                               const float* __restrict__ bias, int biasAlongM,
                                               int K, int swizzleMode) {
    __shared__ __align__(16) ushortT pool[16384];   // 32 KB: [A|B] tiles / epilogue

    int mIdx, nIdx, bz;
    {
        int id = blockIdx.x;
        int r  = id & 7;
        int j  = id >> 3;
        if (swizzleMode == 0) {
            mIdx = r * 32 + j / 6;
            nIdx = j % 6;
            bz   = 0;
        } else {
            int p = r * 32 + (j >> 1);
            bz   = p >> 5;
            nIdx = p & 31;
            mIdx = j & 1;
        }
    }
    const int n0 = nIdx * 128;
    const int m0 = mIdx * 128;
    Bt += (size_t)bz * sBb;

    const int t    = threadIdx.x;
    const int wv   = t >> 6;
    const int lane = t & 63;
    const int lm   = lane & 15;
    const int quad = lane >> 4;
    const int wm   = wv & 1;     // wave's 64-row quadrant (m)
    const int wn   = wv >> 1;    // wave's 64-col quadrant (n)

    ushortT* Als = pool;
    ushortT* Bls = pool + 4096;

    float4v acc[4][4];
#pragma unroll
    for (int i = 0; i < 4; i++)
#pragma unroll
        for (int j = 0; j < 4; j++) { float4v z = {0.f, 0.f, 0.f, 0.f}; acc[i][j] = z; }

    const int nkt = K >> 5;
    for (int kt = 0; kt < nkt; ++kt) {
        __syncthreads();   // previous tile's LDS reads complete before overwrite
#pragma unroll
        for (int j = 0; j < 2; j++) {
            int cid = wv * 128 + j * 64 + lane;   // 16B-chunk id in [0,512)
            int row = cid >> 2;                   // tile row (4 chunks of 8 bf16 per row)
            int c8  = cid & 3;
            int gc  = c8 ^ ((row >> 1) & 3);      // swizzled chunk (same 64B segment)
            const ushortT* ga = A + (size_t)(m0 + row) * K + kt * 32 + gc * 8;
            const ushortT* gb = bHeadMajor
                ? Bt + ((size_t)kt * 32768 + (n0 + row)) * 32 + gc * 8
                : Bt + (size_t)(n0 + row) * ldb + kt * 32 + gc * 8;
            gld_lds16(ga, Als + (size_t)(wv * 128 + j * 64) * 8);
            gld_lds16(gb, Bls + (size_t)(wv * 128 + j * 64) * 8);
        }
        asm volatile("s_waitcnt vmcnt(0)" ::: "memory");
        __syncthreads();

        short8 af[4], bfr[4];
#pragma unroll
        for (int i = 0; i < 4; i++) {
            int r = wm * 64 + i * 16 + lm;
            int slot = quad ^ ((r >> 1) & 3);
            af[i] = *(const short8*)&Als[r * 32 + slot * 8];
        }
#pragma unroll
        for (int j = 0; j < 4; j++) {
            int r = wn * 64 + j * 16 + lm;
            int slot = quad ^ ((r >> 1) & 3);
            bfr[j] = *(const short8*)&Bls[r * 32 + slot * 8];
        }
#pragma unroll
        for (int i = 0; i < 4; i++)
#pragma unroll
            for (int j = 0; j < 4; j++)
                acc[i][j] = __builtin_amdgcn_mfma_f32_16x16x32_bf16(af[i], bfr[j], acc[i][j], 0, 0, 0);
    }

    // epilogue: C/D layout col = lane&15, row = quad*4 + reg
    if (dHeadMajor) {
        __syncthreads();   // all frag reads done before pool overwrite
#pragma unroll
        for (int i = 0; i < 4; i++) {
#pragma unroll
            for (int j = 0; j < 4; j++) {
                int c = wn * 64 + j * 16 + lm;
#pragma unroll
                for (int rg = 0; rg < 4; rg++) {
                    int r = wm * 64 + i * 16 + quad * 4 + rg;
                    float v = acc[i][j][rg] + bias[biasAlongM ? (m0 + r) : (n0 + c)];
                    int chunk = (c >> 3) ^ (r & 7);
                    pool[r * 128 + chunk * 8 + (c & 7)] = f2bf(v);
                }
            }
        }
        __syncthreads();
        ushortT* Dh = (ushortT*)D + (size_t)bz * sDb;
#pragma unroll
        for (int g = 0; g < 4; g++) {
            ushortT* base = Dh + ((size_t)((n0 >> 5) + g) * 32768 + m0) * 32;
#pragma unroll
            for (int it = 0; it < 2; it++) {
                int id = it * 256 + t;          // 0..511
                int r  = id >> 2;
                int cb = id & 3;                // 8-chunk within group
                int pch = (g * 4 + cb) ^ (r & 7);
                ushort8v v = *(const ushort8v*)&pool[r * 128 + pch * 8];
                *(ushort8v*)(base + r * 32 + cb * 8) = v;
            }
        }
    } else {
        float*   Df = (float*)D   + (size_t)bz * sDb;
        ushortT* Dh = (ushortT*)D + (size_t)bz * sDb;
#pragma unroll
        for (int i = 0; i < 4; i++) {
            int r0 = m0 + wm * 64 + i * 16 + quad * 4;
#pragma unroll
            for (int j = 0; j < 4; j++) {
                int c = n0 + wn * 64 + j * 16 + lm;
#pragma unroll
                for (int rg = 0; rg < 4; rg++) {
                    int r = r0 + rg;
                    float v = acc[i][j][rg] + bias[biasAlongM ? r : c];
                    if (outF32) Df[(size_t)r * ldd + c] = v;
                    else        Dh[(size_t)r * ldd + c] = f2bf(v);
                }
            }
        }
    }
}

// ---------------------------------------------------------------------------
// Multi-dilated 3x3 local attention, IN-PLACE on HEAD-MAJOR bf16 qkv:
// qkv[(part*8+hd)*32768 + bp][32], part in {q,k,v}.
// One wave = 64 consecutive pixels (one image row) of ONE head -> all q/k/v
// loads are contiguous 4KB/wave segments; hh bounds are wave-uniform.
// Thread writes only its own q slice (k/v never written) -> race-free.
// ---------------------------------------------------------------------------
__global__ __launch_bounds__(256) void attn_k(ushortT* qkv) {
    const int gt   = blockIdx.x * 256 + threadIdx.x;
    const int lane = gt & 63;
    const int wid  = gt >> 6;          // 0..4095
    const int hd   = wid >> 9;         // 0..7  (512 waves per head)
    const int rowI = wid & 511;        // b*64 + h
    const int b    = rowI >> 6;
    const int h    = rowI & 63;
    const int w    = lane;
    const int dil  = (hd & 3) + 1;     // DILATIONS = [1,2,3,4]
    const int bp   = b * 4096 + h * 64 + w;

    ushortT*       qp    = qkv + ((size_t)hd * 32768 + bp) * 32;
    const ushortT* kbase = qkv + ((size_t)(8  + hd) * 32768 + (size_t)b * 4096) * 32;
    const ushortT* vbase = qkv + ((size_t)(16 + hd) * 32768 + (size_t)b * 4096) * 32;

    float q[32];
#pragma unroll
    for (int c = 0; c < 4; c++) {
        ushort8v v = *(const ushort8v*)(qp + c * 8);
#pragma unroll
        for (int j = 0; j < 8; j++) q[c * 8 + j] = bf2f(v[j]);
    }

    float lgt[9];
    int   nb[9];
    unsigned vmask = 0;
#pragma unroll
    for (int ii = 0; ii < 3; ii++) {
#pragma unroll
        for (int jj = 0; jj < 3; jj++) {
            int idx = ii * 3 + jj;
            int hh = h + (ii - 1) * dil;   // wave-uniform
            int ww = w + (jj - 1) * dil;
            bool ok = ((unsigned)hh < 64u) && ((unsigned)ww < 64u);
            int pp = (hh << 6) + ww;
            nb[idx] = pp;
            float l = 0.f;                 // OOB: k is zero-padded -> logit exactly 0
            if (ok) {
                vmask |= (1u << idx);
                const ushortT* kp = kbase + (size_t)pp * 32;
#pragma unroll
                for (int c = 0; c < 4; c++) {
                    ushort8v v = *(const ushort8v*)(kp + c * 8);
#pragma unroll
                    for (int j = 0; j < 8; j++) l += q[c * 8 + j] * bf2f(v[j]);
                }
                l *= ATT_SCALE;
            }
            lgt[idx] = l;
        }
    }

    float mx = lgt[0];
#pragma unroll
    for (int i = 1; i < 9; i++) mx = fmaxf(mx, lgt[i]);
    float e[9], s = 0.f;
#pragma unroll
    for (int i = 0; i < 9; i++) { e[i] = __expf(lgt[i] - mx); s += e[i]; }
    const float inv = 1.f / s;

    float acc[32];
#pragma unroll
    for (int d = 0; d < 32; d++) acc[d] = 0.f;
#pragma unroll
    for (int idx = 0; idx < 9; idx++) {
        if ((vmask >> idx) & 1u) {        // OOB: v = 0, contributes nothing (e[idx] stays in s)
            float pj = e[idx] * inv;
            const ushortT* vp = vbase + (size_t)nb[idx] * 32;
#pragma unroll
            for (int c = 0; c < 4; c++) {
                ushort8v v = *(const ushort8v*)(vp + c * 8);
#pragma unroll
                for (int j = 0; j < 8; j++) acc[c * 8 + j] += pj * bf2f(v[j]);
            }
        }
    }

#pragma unroll
    for (int c = 0; c < 4; c++) {         // overwrite own q slice
        ushort8v v;
#pragma unroll
        for (int j = 0; j < 8; j++) v[j] = f2bf(acc[c * 8 + j]);
        *(ushort8v*)(qp + c * 8) = v;
    }
}

// ---------------------------------------------------------------------------
extern "C" void kernel_launch(void* const* d_in, const int* in_sizes, int n_in,
                              void* d_out, int out_size, void* d_ws, size_t ws_size,
                              hipStream_t stream) {
    const float* x      = (const float*)d_in[0];  // (8,256,64,64) fp32
    const float* w_qkv  = (const float*)d_in[1];  // (768,256)
    const float* b_qkv  = (const float*)d_in[2];  // (768,)
    const float* w_proj = (const float*)d_in[3];  // (256,256)
    const float* b_proj = (const float*)d_in[4];  // (256,)

    // ws layout (256B-aligned): bqF | bpF | wqkvB | wprojB | qkv(head-major)
    char* ws = (char*)d_ws;
    float*   bqF    = (float*)(ws + 256);              // 768 f32
    float*   bpF    = (float*)(ws + 3328);             // 256 f32
    ushortT* wqkvB  = (ushortT*)(ws + 4352);           // 196608 bf16
    ushortT* wprojB = (ushortT*)(ws + 397568);         // 65536 bf16
    ushortT* qkv    = (ushortT*)(ws + 528640);         // 24 x 32768 x 32 bf16 = 48 MiB
    ushortT* xT     = (ushortT*)d_out;                 // (32768,256) bf16 scratch in d_out;
                                                       // fully overwritten by the final GEMM

    // 0) weights -> bf16, biases -> fp32
    convert_params<<<1028, 256, 0, stream>>>(w_qkv, w_proj, b_qkv, b_proj,
                                             wqkvB, wprojB, bqF, bpF);

    // 1) x (B,C,P) -> xT (B,P,C) bf16
    transpose_cp<<<dim3(4, 64, 8), 256, 0, stream>>>(x, xT);

    // 2) qkv head-major = xT(32768,256) @ w_qkv^T + b_qkv   (bias along n)
    //    1536 blocks, XCD swizzle mode 0 (6 n-blocks per A-tile share an XCD)
    gemm_bt<<<dim3(1536), 256, 0, stream>>>(xT, wqkvB, 0, 256, 0,
                                            qkv, 0, 0, 1, 0,
                                            bqF, 0, 256, 0);

    // 3) attention in-place on head-major qkv (y overwrites q slices)
    attn_k<<<dim3(1024), 256, 0, stream>>>(qkv);

    // 4) out(b,256,4096) fp32 = w_proj @ y(b)^T + b_proj  (bias along m)
    //    512 blocks, XCD swizzle mode 1 (2 m-blocks per y-tile share an XCD)
    gemm_bt<<<dim3(512), 256, 0, stream>>>(wprojB, qkv, (long long)4096 * 32, 0, 1,
                                           d_out, (long long)256 * 4096, 4096, 0, 1,
                                           bpF, 1, 256, 1);
}

// Round 9
// 173.037 us; speedup vs baseline: 1.1870x; 1.0306x over previous
//
#include <hip/hip_runtime.h>
#include <cstdint>

typedef unsigned short ushortT;
typedef __attribute__((ext_vector_type(8))) short short8;      // 8 bf16 = 4 VGPRs (MFMA A/B frag)
typedef __attribute__((ext_vector_type(8))) unsigned short ushort8v;
typedef __attribute__((ext_vector_type(4))) float float4v;

#define ATT_SCALE 0.17677669529663687f   // 32^-0.5

__device__ inline float bf2f(unsigned short u) {
    union { unsigned int i; float f; } x; x.i = ((unsigned int)u) << 16; return x.f;
}
__device__ inline unsigned short f2bf(float f) {
    union { float f; unsigned int i; } x; x.f = f;
    unsigned int i = x.i;
    i += 0x7fffu + ((i >> 16) & 1u);      // RNE
    return (unsigned short)(i >> 16);
}

__device__ inline void gld_lds16(const ushortT* g, ushortT* l) {
    // async global->LDS, 16B/lane; LDS dest = wave-uniform base + lane*16
    __builtin_amdgcn_global_load_lds((const __attribute__((address_space(1))) void*)g,
                                     (__attribute__((address_space(3))) void*)l, 16, 0, 0);
}

// ---------------------------------------------------------------------------
// Transpose+convert (B, 256, 4096) fp32 -> (B, 4096, 256) bf16, AND (in the
// first 1028 blocks) convert weights->bf16 / biases->fp32 (folded kernel —
// saves a dispatch). grid (4,64,8), block 256. xT lives in d_out (dead until
// the final projection GEMM overwrites every element).
// ---------------------------------------------------------------------------
__global__ __launch_bounds__(256) void transpose_cp(const float* __restrict__ x,
                                                    ushortT* __restrict__ xT,
                                                    const float* __restrict__ w_qkv,
                                                    const float* __restrict__ w_proj,
                                                    const float* __restrict__ b_qkv,
                                                    const float* __restrict__ b_proj,
                                                    ushortT* __restrict__ wqkvB,
                                                    ushortT* __restrict__ wprojB,
                                                    float* __restrict__ bqF,
                                                    float* __restrict__ bpF) {
    __shared__ __align__(16) ushortT tile[64][65];
    const int b  = blockIdx.z;
    const int c0 = blockIdx.x * 64;
    const int p0 = blockIdx.y * 64;
    const int t  = threadIdx.x;

    // folded param conversion (1 MB total, spread over 1028 blocks)
    {
        int flat = blockIdx.x + 4 * blockIdx.y + 256 * blockIdx.z;   // 0..2047
        if (flat < 1028) {
            int i = flat * 256 + t;
            if (i < 196608) {
                wqkvB[i] = f2bf(w_qkv[i]);
            } else if (i < 262144) {
                wprojB[i - 196608] = f2bf(w_proj[i - 196608]);
            } else if (i < 262912) {
                bqF[i - 262144] = b_qkv[i - 262144];
            } else if (i < 263168) {
                bpF[i - 262912] = b_proj[i - 262912];
            }
        }
    }

    const float* xb = x + (size_t)b * 256 * 4096;
#pragma unroll
    for (int it = 0; it < 4; it++) {
        int id  = t + it * 256;          // 0..1023
        int row = id >> 4;               // c row 0..63
        int c4  = (id & 15) * 4;         // p chunk of 4 floats
        float4 v = *(const float4*)(xb + (size_t)(c0 + row) * 4096 + p0 + c4);
        tile[row][c4 + 0] = f2bf(v.x);
        tile[row][c4 + 1] = f2bf(v.y);
        tile[row][c4 + 2] = f2bf(v.z);
        tile[row][c4 + 3] = f2bf(v.w);
    }
    __syncthreads();
    ushortT* xTb = xT + (size_t)b * 4096 * 256;
#pragma unroll
    for (int it = 0; it < 2; it++) {
        int id   = t + it * 256;             // 0..511
        int prow = id >> 3;                  // p row 0..63
        int cc   = (id & 7) * 8;             // c chunk
        ushort8v v;
#pragma unroll
        for (int j = 0; j < 8; j++) v[j] = tile[cc + j][prow];
        *(ushort8v*)(xTb + (size_t)(p0 + prow) * 256 + c0 + cc) = v;
    }
}

// ---------------------------------------------------------------------------
// GEMM  D[m][n] = sum_k A[m][k] * Bt[n][k]  + bias   (bf16 in, fp32 acc)
// R5/R8 structure: 2-barrier staged K-loop, global_load_lds w=16, XOR-chunk
// LDS swizzle, XCD-aware block swizzle (blocks sharing a tile -> same id%8).
// Epilogues (all via the 32 KB pool, fully-coalesced 16B stores):
//   dHeadMajor: bf16 head-major D[((c>>5)*32768+r)*32+(c&31)] (one pass).
//   outF32 row-major: fp32, TWO row-half passes of 64x128 f32 (32 KB) with
//     +4r column-rotation (2-way bank aliasing = free), float4 stores.
// ---------------------------------------------------------------------------
__global__ __launch_bounds__(256) void gemm_bt(const ushortT* __restrict__ A,
                                               const ushortT* __restrict__ Bt, long long sBb,
                                               int ldb, int bHeadMajor,
                                               void* __restrict__ D, long long sDb,
                                               int ldd, int dHeadMajor, int outF32,
                                               const float* __restrict__ bias, int biasAlongM,
                                               int K, int swizzleMode) {
    __shared__ __align__(16) ushortT pool[16384];   // 32 KB: [A|B] tiles / epilogue

    int mIdx, nIdx, bz;
    {
        int id = blockIdx.x;
        int r  = id & 7;
        int j  = id >> 3;
        if (swizzleMode == 0) {
            mIdx = r * 32 + j / 6;     // 6 n-blocks sharing an A-tile -> same XCD
            nIdx = j % 6;
            bz   = 0;
        } else {
            int p = r * 32 + (j >> 1); // 2 m-blocks sharing a y-tile -> same XCD
            bz   = p >> 5;
            nIdx = p & 31;
            mIdx = j & 1;
        }
    }
    const int n0 = nIdx * 128;
    const int m0 = mIdx * 128;
    Bt += (size_t)bz * sBb;

    const int t    = threadIdx.x;
    const int wv   = t >> 6;
    const int lane = t & 63;
    const int lm   = lane & 15;
    const int quad = lane >> 4;
    const int wm   = wv & 1;     // wave's 64-row quadrant (m)
    const int wn   = wv >> 1;    // wave's 64-col quadrant (n)

    ushortT* Als = pool;
    ushortT* Bls = pool + 4096;

    float4v acc[4][4];
#pragma unroll
    for (int i = 0; i < 4; i++)
#pragma unroll
        for (int j = 0; j < 4; j++) { float4v z = {0.f, 0.f, 0.f, 0.f}; acc[i][j] = z; }

    const int nkt = K >> 5;
    for (int kt = 0; kt < nkt; ++kt) {
        __syncthreads();   // previous tile's LDS reads complete before overwrite
#pragma unroll
        for (int j = 0; j < 2; j++) {
            int cid = wv * 128 + j * 64 + lane;   // 16B-chunk id in [0,512)
            int row = cid >> 2;                   // tile row (4 chunks of 8 bf16 per row)
            int c8  = cid & 3;
            int gc  = c8 ^ ((row >> 1) & 3);      // swizzled chunk (same 64B segment)
            const ushortT* ga = A + (size_t)(m0 + row) * K + kt * 32 + gc * 8;
            const ushortT* gb = bHeadMajor
                ? Bt + ((size_t)kt * 32768 + (n0 + row)) * 32 + gc * 8
                : Bt + (size_t)(n0 + row) * ldb + kt * 32 + gc * 8;
            gld_lds16(ga, Als + (size_t)(wv * 128 + j * 64) * 8);
            gld_lds16(gb, Bls + (size_t)(wv * 128 + j * 64) * 8);
        }
        asm volatile("s_waitcnt vmcnt(0)" ::: "memory");
        __syncthreads();

        short8 af[4], bfr[4];
#pragma unroll
        for (int i = 0; i < 4; i++) {
            int r = wm * 64 + i * 16 + lm;
            int slot = quad ^ ((r >> 1) & 3);
            af[i] = *(const short8*)&Als[r * 32 + slot * 8];
        }
#pragma unroll
        for (int j = 0; j < 4; j++) {
            int r = wn * 64 + j * 16 + lm;
            int slot = quad ^ ((r >> 1) & 3);
            bfr[j] = *(const short8*)&Bls[r * 32 + slot * 8];
        }
#pragma unroll
        for (int i = 0; i < 4; i++)
#pragma unroll
            for (int j = 0; j < 4; j++)
                acc[i][j] = __builtin_amdgcn_mfma_f32_16x16x32_bf16(af[i], bfr[j], acc[i][j], 0, 0, 0);
    }

    // epilogue: C/D layout col = lane&15, row = quad*4 + reg
    if (dHeadMajor) {
        __syncthreads();   // all frag reads done before pool overwrite
#pragma unroll
        for (int i = 0; i < 4; i++) {
#pragma unroll
            for (int j = 0; j < 4; j++) {
                int c = wn * 64 + j * 16 + lm;
#pragma unroll
                for (int rg = 0; rg < 4; rg++) {
                    int r = wm * 64 + i * 16 + quad * 4 + rg;
                    float v = acc[i][j][rg] + bias[biasAlongM ? (m0 + r) : (n0 + c)];
                    int chunk = (c >> 3) ^ (r & 7);
                    pool[r * 128 + chunk * 8 + (c & 7)] = f2bf(v);
                }
            }
        }
        __syncthreads();
        ushortT* Dh = (ushortT*)D + (size_t)bz * sDb;
#pragma unroll
        for (int g = 0; g < 4; g++) {
            ushortT* base = Dh + ((size_t)((n0 >> 5) + g) * 32768 + m0) * 32;
#pragma unroll
            for (int it = 0; it < 2; it++) {
                int id = it * 256 + t;          // 0..511
                int r  = id >> 2;
                int cb = id & 3;                // 8-chunk within group
                int pch = (g * 4 + cb) ^ (r & 7);
                ushort8v v = *(const ushort8v*)&pool[r * 128 + pch * 8];
                *(ushort8v*)(base + r * 32 + cb * 8) = v;
            }
        }
    } else if (outF32) {
        // Two row-half passes: stage 64x128 fp32 (32 KB) with +4r column
        // rotation, then fully-coalesced float4 stores (512 B per row).
        float* poolF = (float*)pool;
        float* Df = (float*)D + (size_t)bz * sDb;
#pragma unroll
        for (int pass = 0; pass < 2; pass++) {
            __syncthreads();   // prior pool use (tiles / prev pass) complete
            if (wm == pass) {
#pragma unroll
                for (int i = 0; i < 4; i++) {
#pragma unroll
                    for (int j = 0; j < 4; j++) {
                        int c = wn * 64 + j * 16 + lm;
#pragma unroll
                        for (int rg = 0; rg < 4; rg++) {
                            int r64 = i * 16 + quad * 4 + rg;    // 0..63
                            float v = acc[i][j][rg] +
                                      bias[biasAlongM ? (m0 + pass * 64 + r64) : (n0 + c)];
                            int phys = (c + 4 * r64) & 127;      // rotation: 2-way banks
                            poolF[r64 * 128 + phys] = v;
                        }
                    }
                }
            }
            __syncthreads();
#pragma unroll
            for (int it = 0; it < 8; it++) {
                int id  = it * 256 + t;          // 0..2047
                int r64 = id >> 5;               // 0..63
                int c   = (id & 31) * 4;         // logical float4 col
                int phys = (c + 4 * r64) & 127;  // stays 16B-aligned (c,4r ≡ 0 mod 4)
                float4 v = *(const float4*)&poolF[r64 * 128 + phys];
                *(float4*)&Df[(size_t)(m0 + pass * 64 + r64) * ldd + n0 + c] = v;
            }
        }
    } else {
        ushortT* Dh = (ushortT*)D + (size_t)bz * sDb;
#pragma unroll
        for (int i = 0; i < 4; i++) {
            int r0 = m0 + wm * 64 + i * 16 + quad * 4;
#pragma unroll
            for (int j = 0; j < 4; j++) {
                int c = n0 + wn * 64 + j * 16 + lm;
#pragma unroll
                for (int rg = 0; rg < 4; rg++) {
                    int r = r0 + rg;
                    float v = acc[i][j][rg] + bias[biasAlongM ? r : c];
                    Dh[(size_t)r * ldd + c] = f2bf(v);
                }
            }
        }
    }
}

// ---------------------------------------------------------------------------
// Multi-dilated 3x3 local attention, IN-PLACE on HEAD-MAJOR bf16 qkv:
// qkv[(part*8+hd)*32768 + bp][32], part in {q,k,v}.
// One wave = 64 consecutive pixels (one image row) of ONE head -> all q/k/v
// loads are contiguous 4KB/wave segments; hh bounds are wave-uniform.
// Thread writes only its own q slice (k/v never written) -> race-free.
// ---------------------------------------------------------------------------
__global__ __launch_bounds__(256) void attn_k(ushortT* qkv) {
    const int gt   = blockIdx.x * 256 + threadIdx.x;
    const int lane = gt & 63;
    const int wid  = gt >> 6;          // 0..4095
    const int hd   = wid >> 9;         // 0..7  (512 waves per head)
    const int rowI = wid & 511;        // b*64 + h
    const int b    = rowI >> 6;
    const int h    = rowI & 63;
    const int w    = lane;
    const int dil  = (hd & 3) + 1;     // DILATIONS = [1,2,3,4]
    const int bp   = b * 4096 + h * 64 + w;

    ushortT*       qp    = qkv + ((size_t)hd * 32768 + bp) * 32;
    const ushortT* kbase = qkv + ((size_t)(8  + hd) * 32768 + (size_t)b * 4096) * 32;
    const ushortT* vbase = qkv + ((size_t)(16 + hd) * 32768 + (size_t)b * 4096) * 32;

    float q[32];
#pragma unroll
    for (int c = 0; c < 4; c++) {
        ushort8v v = *(const ushort8v*)(qp + c * 8);
#pragma unroll
        for (int j = 0; j < 8; j++) q[c * 8 + j] = bf2f(v[j]);
    }

    float lgt[9];
    int   nb[9];
    unsigned vmask = 0;
#pragma unroll
    for (int ii = 0; ii < 3; ii++) {
#pragma unroll
        for (int jj = 0; jj < 3; jj++) {
            int idx = ii * 3 + jj;
            int hh = h + (ii - 1) * dil;   // wave-uniform
            int ww = w + (jj - 1) * dil;
            bool ok = ((unsigned)hh < 64u) && ((unsigned)ww < 64u);
            int pp = (hh << 6) + ww;
            nb[idx] = pp;
            float l = 0.f;                 // OOB: k is zero-padded -> logit exactly 0
            if (ok) {
                vmask |= (1u << idx);
                const ushortT* kp = kbase + (size_t)pp * 32;
#pragma unroll
                for (int c = 0; c < 4; c++) {
                    ushort8v v = *(const ushort8v*)(kp + c * 8);
#pragma unroll
                    for (int j = 0; j < 8; j++) l += q[c * 8 + j] * bf2f(v[j]);
                }
                l *= ATT_SCALE;
            }
            lgt[idx] = l;
        }
    }

    float mx = lgt[0];
#pragma unroll
    for (int i = 1; i < 9; i++) mx = fmaxf(mx, lgt[i]);
    float e[9], s = 0.f;
#pragma unroll
    for (int i = 0; i < 9; i++) { e[i] = __expf(lgt[i] - mx); s += e[i]; }
    const float inv = 1.f / s;

    float acc[32];
#pragma unroll
    for (int d = 0; d < 32; d++) acc[d] = 0.f;
#pragma unroll
    for (int idx = 0; idx < 9; idx++) {
        if ((vmask >> idx) & 1u) {        // OOB: v = 0, contributes nothing (e[idx] stays in s)
            float pj = e[idx] * inv;
            const ushortT* vp = vbase + (size_t)nb[idx] * 32;
#pragma unroll
            for (int c = 0; c < 4; c++) {
                ushort8v v = *(const ushort8v*)(vp + c * 8);
#pragma unroll
                for (int j = 0; j < 8; j++) acc[c * 8 + j] += pj * bf2f(v[j]);
            }
        }
    }

#pragma unroll
    for (int c = 0; c < 4; c++) {         // overwrite own q slice
        ushort8v v;
#pragma unroll
        for (int j = 0; j < 8; j++) v[j] = f2bf(acc[c * 8 + j]);
        *(ushort8v*)(qp + c * 8) = v;
    }
}

// ---------------------------------------------------------------------------
extern "C" void kernel_launch(void* const* d_in, const int* in_sizes, int n_in,
                              void* d_out, int out_size, void* d_ws, size_t ws_size,
                              hipStream_t stream) {
    const float* x      = (const float*)d_in[0];  // (8,256,64,64) fp32
    const float* w_qkv  = (const float*)d_in[1];  // (768,256)
    const float* b_qkv  = (const float*)d_in[2];  // (768,)
    const float* w_proj = (const float*)d_in[3];  // (256,256)
    const float* b_proj = (const float*)d_in[4];  // (256,)

    // ws layout (256B-aligned): bqF | bpF | wqkvB | wprojB | qkv(head-major)
    char* ws = (char*)d_ws;
    float*   bqF    = (float*)(ws + 256);              // 768 f32
    float*   bpF    = (float*)(ws + 3328);             // 256 f32
    ushortT* wqkvB  = (ushortT*)(ws + 4352);           // 196608 bf16
    ushortT* wprojB = (ushortT*)(ws + 397568);         // 65536 bf16
    ushortT* qkv    = (ushortT*)(ws + 528640);         // 24 x 32768 x 32 bf16 = 48 MiB
    ushortT* xT     = (ushortT*)d_out;                 // (32768,256) bf16 scratch in d_out;
                                                       // fully overwritten by the final GEMM

    // 1) x (B,C,P) -> xT (B,P,C) bf16  +  folded param conversion
    transpose_cp<<<dim3(4, 64, 8), 256, 0, stream>>>(x, xT, w_qkv, w_proj, b_qkv, b_proj,
                                                     wqkvB, wprojB, bqF, bpF);

    // 2) qkv head-major = xT(32768,256) @ w_qkv^T + b_qkv   (bias along n)
    //    1536 blocks, XCD swizzle mode 0 (6 n-blocks per A-tile share an XCD)
    gemm_bt<<<dim3(1536), 256, 0, stream>>>(xT, wqkvB, 0, 256, 0,
                                            qkv, 0, 0, 1, 0,
                                            bqF, 0, 256, 0);

    // 3) attention in-place on head-major qkv (y overwrites q slices)
    attn_k<<<dim3(1024), 256, 0, stream>>>(qkv);

    // 4) out(b,256,4096) fp32 = w_proj @ y(b)^T + b_proj  (bias along m)
    //    512 blocks, XCD swizzle mode 1 (2 m-blocks per y-tile share an XCD)
    gemm_bt<<<dim3(512), 256, 0, stream>>>(wprojB, qkv, (long long)4096 * 32, 0, 1,
                                           d_out, (long long)256 * 4096, 4096, 0, 1,
                                           bpF, 1, 256, 1);
}

// Round 10
// 168.330 us; speedup vs baseline: 1.2201x; 1.0280x over previous
//
#include <hip/hip_runtime.h>
#include <cstdint>

typedef unsigned short ushortT;
typedef __attribute__((ext_vector_type(8))) short short8;      // 8 bf16 = 4 VGPRs (MFMA A/B frag)
typedef __attribute__((ext_vector_type(8))) unsigned short ushort8v;
typedef __attribute__((ext_vector_type(4))) float float4v;

#define ATT_SCALE 0.17677669529663687f   // 32^-0.5

__device__ inline float bf2f(unsigned short u) {
    union { unsigned int i; float f; } x; x.i = ((unsigned int)u) << 16; return x.f;
}
__device__ inline unsigned short f2bf(float f) {
    union { float f; unsigned int i; } x; x.f = f;
    unsigned int i = x.i;
    i += 0x7fffu + ((i >> 16) & 1u);      // RNE
    return (unsigned short)(i >> 16);
}

__device__ inline void gld_lds16(const ushortT* g, ushortT* l) {
    // async global->LDS, 16B/lane; LDS dest = wave-uniform base + lane*16
    __builtin_amdgcn_global_load_lds((const __attribute__((address_space(1))) void*)g,
                                     (__attribute__((address_space(3))) void*)l, 16, 0, 0);
}

// ---------------------------------------------------------------------------
// Transpose+convert (B, 256, 4096) fp32 -> (B, 4096, 256) bf16, AND (in the
// first 1028 blocks) convert weights->bf16 / biases->fp32 (folded kernel).
// grid (4,64,8), block 256. xT lives in d_out (dead until the final
// projection GEMM overwrites every element).
// ---------------------------------------------------------------------------
__global__ __launch_bounds__(256) void transpose_cp(const float* __restrict__ x,
                                                    ushortT* __restrict__ xT,
                                                    const float* __restrict__ w_qkv,
                                                    const float* __restrict__ w_proj,
                                                    const float* __restrict__ b_qkv,
                                                    const float* __restrict__ b_proj,
                                                    ushortT* __restrict__ wqkvB,
                                                    ushortT* __restrict__ wprojB,
                                                    float* __restrict__ bqF,
                                                    float* __restrict__ bpF) {
    __shared__ __align__(16) ushortT tile[64][65];
    const int b  = blockIdx.z;
    const int c0 = blockIdx.x * 64;
    const int p0 = blockIdx.y * 64;
    const int t  = threadIdx.x;

    // folded param conversion (1 MB total, spread over 1028 blocks)
    {
        int flat = blockIdx.x + 4 * blockIdx.y + 256 * blockIdx.z;   // 0..2047
        if (flat < 1028) {
            int i = flat * 256 + t;
            if (i < 196608) {
                wqkvB[i] = f2bf(w_qkv[i]);
            } else if (i < 262144) {
                wprojB[i - 196608] = f2bf(w_proj[i - 196608]);
            } else if (i < 262912) {
                bqF[i - 262144] = b_qkv[i - 262144];
            } else if (i < 263168) {
                bpF[i - 262912] = b_proj[i - 262912];
            }
        }
    }

    const float* xb = x + (size_t)b * 256 * 4096;
#pragma unroll
    for (int it = 0; it < 4; it++) {
        int id  = t + it * 256;          // 0..1023
        int row = id >> 4;               // c row 0..63
        int c4  = (id & 15) * 4;         // p chunk of 4 floats
        float4 v = *(const float4*)(xb + (size_t)(c0 + row) * 4096 + p0 + c4);
        tile[row][c4 + 0] = f2bf(v.x);
        tile[row][c4 + 1] = f2bf(v.y);
        tile[row][c4 + 2] = f2bf(v.z);
        tile[row][c4 + 3] = f2bf(v.w);
    }
    __syncthreads();
    ushortT* xTb = xT + (size_t)b * 4096 * 256;
#pragma unroll
    for (int it = 0; it < 2; it++) {
        int id   = t + it * 256;             // 0..511
        int prow = id >> 3;                  // p row 0..63
        int cc   = (id & 7) * 8;             // c chunk
        ushort8v v;
#pragma unroll
        for (int j = 0; j < 8; j++) v[j] = tile[cc + j][prow];
        *(ushort8v*)(xTb + (size_t)(p0 + prow) * 256 + c0 + cc) = v;
    }
}

// ---------------------------------------------------------------------------
// GEMM  D[m][n] = sum_k A[m][k] * Bt[n][k]  + bias   (bf16 in, fp32 acc)
// BK=64 variant of the measured-best R5 loop: A-tile 128x64 + B-tile 128x64
// = 32 KB (same LDS/occupancy as BK=32) but HALF the barrier convoys
// (4 stages for K=256), 32 MFMA per stage.
// LDS layout: row r (stride 64 elems = 128 B), 8 chunk-slots of 8 bf16;
// content at slot s = global chunk (s ^ (r&7))  -> frag reads at
// slot (k8 ^ (r&7)) give 2 rows/slot = 2-way bank aliasing (free).
// XCD-aware block swizzle: blocks sharing a tile land on the same id%8 XCD.
// Epilogues via 32 KB pool, fully-coalesced 16B stores:
//   dHeadMajor: bf16 head-major D[((c>>5)*32768+r)*32+(c&31)] (one pass).
//   outF32 row-major: TWO row-half passes of 64x128 f32 with +4r rotation.
// ---------------------------------------------------------------------------
__global__ __launch_bounds__(256) void gemm_bt(const ushortT* __restrict__ A,
                                               const ushortT* __restrict__ Bt, long long sBb,
                                               int ldb, int bHeadMajor,
                                               void* __restrict__ D, long long sDb,
                                               int ldd, int dHeadMajor, int outF32,
                                               const float* __restrict__ bias, int biasAlongM,
                                               int K, int swizzleMode) {
    __shared__ __align__(16) ushortT pool[16384];   // 32 KB: [A(16K)|B(16K)] / epilogue

    int mIdx, nIdx, bz;
    {
        int id = blockIdx.x;
        int r  = id & 7;
        int j  = id >> 3;
        if (swizzleMode == 0) {
            mIdx = r * 32 + j / 6;     // 6 n-blocks sharing an A-tile -> same XCD
            nIdx = j % 6;
            bz   = 0;
        } else {
            int p = r * 32 + (j >> 1); // 2 m-blocks sharing a y-tile -> same XCD
            bz   = p >> 5;
            nIdx = p & 31;
            mIdx = j & 1;
        }
    }
    const int n0 = nIdx * 128;
    const int m0 = mIdx * 128;
    Bt += (size_t)bz * sBb;

    const int t    = threadIdx.x;
    const int wv   = t >> 6;
    const int lane = t & 63;
    const int lm   = lane & 15;
    const int quad = lane >> 4;
    const int wm   = wv & 1;     // wave's 64-row quadrant (m)
    const int wn   = wv >> 1;    // wave's 64-col quadrant (n)

    ushortT* Als = pool;            // 128 rows x 64 elems
    ushortT* Bls = pool + 8192;

    float4v acc[4][4];
#pragma unroll
    for (int i = 0; i < 4; i++)
#pragma unroll
        for (int j = 0; j < 4; j++) { float4v z = {0.f, 0.f, 0.f, 0.f}; acc[i][j] = z; }

    const int nkt = K >> 6;          // BK=64
    for (int kt = 0; kt < nkt; ++kt) {
        __syncthreads();   // previous stage's LDS reads complete before overwrite
        // stage: 1024 16B-chunks per operand; each wave 256 chunks (4 iters)
#pragma unroll
        for (int j = 0; j < 4; j++) {
            int cid = wv * 256 + j * 64 + lane;   // chunk id in [0,1024)
            int row = cid >> 3;                   // tile row (8 chunks of 8 bf16 per row)
            int s   = cid & 7;                    // physical slot
            int gc  = s ^ (row & 7);              // global chunk (perm within 128B row)
            const ushortT* ga = A + (size_t)(m0 + row) * K + kt * 64 + gc * 8;
            const ushortT* gb = bHeadMajor
                ? Bt + ((size_t)(kt * 2 + (gc >> 2)) * 32768 + (n0 + row)) * 32 + (gc & 3) * 8
                : Bt + (size_t)(n0 + row) * ldb + kt * 64 + gc * 8;
            gld_lds16(ga, Als + (size_t)(wv * 256 + j * 64) * 8);
            gld_lds16(gb, Bls + (size_t)(wv * 256 + j * 64) * 8);
        }
        asm volatile("s_waitcnt vmcnt(0)" ::: "memory");
        __syncthreads();

#pragma unroll
        for (int g = 0; g < 2; g++) {            // k-group: k = g*32 .. g*32+31
            short8 af[4], bfr[4];
#pragma unroll
            for (int i = 0; i < 4; i++) {
                int r = wm * 64 + i * 16 + lm;
                int slot = (g * 4 + quad) ^ (r & 7);
                af[i] = *(const short8*)&Als[r * 64 + slot * 8];
            }
#pragma unroll
            for (int j = 0; j < 4; j++) {
                int r = wn * 64 + j * 16 + lm;
                int slot = (g * 4 + quad) ^ (r & 7);
                bfr[j] = *(const short8*)&Bls[r * 64 + slot * 8];
            }
#pragma unroll
            for (int i = 0; i < 4; i++)
#pragma unroll
                for (int j = 0; j < 4; j++)
                    acc[i][j] = __builtin_amdgcn_mfma_f32_16x16x32_bf16(af[i], bfr[j], acc[i][j], 0, 0, 0);
        }
    }

    // epilogue: C/D layout col = lane&15, row = quad*4 + reg
    if (dHeadMajor) {
        __syncthreads();   // all frag reads done before pool overwrite
#pragma unroll
        for (int i = 0; i < 4; i++) {
#pragma unroll
            for (int j = 0; j < 4; j++) {
                int c = wn * 64 + j * 16 + lm;
#pragma unroll
                for (int rg = 0; rg < 4; rg++) {
                    int r = wm * 64 + i * 16 + quad * 4 + rg;
                    float v = acc[i][j][rg] + bias[biasAlongM ? (m0 + r) : (n0 + c)];
                    int chunk = (c >> 3) ^ (r & 7);
                    pool[r * 128 + chunk * 8 + (c & 7)] = f2bf(v);
                }
            }
        }
        __syncthreads();
        ushortT* Dh = (ushortT*)D + (size_t)bz * sDb;
#pragma unroll
        for (int g = 0; g < 4; g++) {
            ushortT* base = Dh + ((size_t)((n0 >> 5) + g) * 32768 + m0) * 32;
#pragma unroll
            for (int it = 0; it < 2; it++) {
                int id = it * 256 + t;          // 0..511
                int r  = id >> 2;
                int cb = id & 3;                // 8-chunk within group
                int pch = (g * 4 + cb) ^ (r & 7);
                ushort8v v = *(const ushort8v*)&pool[r * 128 + pch * 8];
                *(ushort8v*)(base + r * 32 + cb * 8) = v;
            }
        }
    } else if (outF32) {
        // Two row-half passes: stage 64x128 fp32 (32 KB) with +4r column
        // rotation, then fully-coalesced float4 stores (512 B per row).
        float* poolF = (float*)pool;
        float* Df = (float*)D + (size_t)bz * sDb;
#pragma unroll
        for (int pass = 0; pass < 2; pass++) {
            __syncthreads();   // prior pool use (tiles / prev pass) complete
            if (wm == pass) {
#pragma unroll
                for (int i = 0; i < 4; i++) {
#pragma unroll
                    for (int j = 0; j < 4; j++) {
                        int c = wn * 64 + j * 16 + lm;
#pragma unroll
                        for (int rg = 0; rg < 4; rg++) {
                            int r64 = i * 16 + quad * 4 + rg;    // 0..63
                            float v = acc[i][j][rg] +
                                      bias[biasAlongM ? (m0 + pass * 64 + r64) : (n0 + c)];
                            int phys = (c + 4 * r64) & 127;      // rotation: 2-way banks
                            poolF[r64 * 128 + phys] = v;
                        }
                    }
                }
            }
            __syncthreads();
#pragma unroll
            for (int it = 0; it < 8; it++) {
                int id  = it * 256 + t;          // 0..2047
                int r64 = id >> 5;               // 0..63
                int c   = (id & 31) * 4;         // logical float4 col
                int phys = (c + 4 * r64) & 127;  // stays 16B-aligned
                float4 v = *(const float4*)&poolF[r64 * 128 + phys];
                *(float4*)&Df[(size_t)(m0 + pass * 64 + r64) * ldd + n0 + c] = v;
            }
        }
    } else {
        ushortT* Dh = (ushortT*)D + (size_t)bz * sDb;
#pragma unroll
        for (int i = 0; i < 4; i++) {
            int r0 = m0 + wm * 64 + i * 16 + quad * 4;
#pragma unroll
            for (int j = 0; j < 4; j++) {
                int c = n0 + wn * 64 + j * 16 + lm;
#pragma unroll
                for (int rg = 0; rg < 4; rg++) {
                    int r = r0 + rg;
                    float v = acc[i][j][rg] + bias[biasAlongM ? r : c];
                    Dh[(size_t)r * ldd + c] = f2bf(v);
                }
            }
        }
    }
}

// ---------------------------------------------------------------------------
// Multi-dilated 3x3 local attention, IN-PLACE on HEAD-MAJOR bf16 qkv:
// qkv[(part*8+hd)*32768 + bp][32], part in {q,k,v}.
// One wave = 64 consecutive pixels (one image row) of ONE head -> all q/k/v
// loads are contiguous 4KB/wave segments; hh bounds are wave-uniform.
// Thread writes only its own q slice (k/v never written) -> race-free.
// ---------------------------------------------------------------------------
__global__ __launch_bounds__(256) void attn_k(ushortT* qkv) {
    const int gt   = blockIdx.x * 256 + threadIdx.x;
    const int lane = gt & 63;
    const int wid  = gt >> 6;          // 0..4095
    const int hd   = wid >> 9;         // 0..7  (512 waves per head)
    const int rowI = wid & 511;        // b*64 + h
    const int b    = rowI >> 6;
    const int h    = rowI & 63;
    const int w    = lane;
    const int dil  = (hd & 3) + 1;     // DILATIONS = [1,2,3,4]
    const int bp   = b * 4096 + h * 64 + w;

    ushortT*       qp    = qkv + ((size_t)hd * 32768 + bp) * 32;
    const ushortT* kbase = qkv + ((size_t)(8  + hd) * 32768 + (size_t)b * 4096) * 32;
    const ushortT* vbase = qkv + ((size_t)(16 + hd) * 32768 + (size_t)b * 4096) * 32;

    float q[32];
#pragma unroll
    for (int c = 0; c < 4; c++) {
        ushort8v v = *(const ushort8v*)(qp + c * 8);
#pragma unroll
        for (int j = 0; j < 8; j++) q[c * 8 + j] = bf2f(v[j]);
    }

    float lgt[9];
    int   nb[9];
    unsigned vmask = 0;
#pragma unroll
    for (int ii = 0; ii < 3; ii++) {
#pragma unroll
        for (int jj = 0; jj < 3; jj++) {
            int idx = ii * 3 + jj;
            int hh = h + (ii - 1) * dil;   // wave-uniform
            int ww = w + (jj - 1) * dil;
            bool ok = ((unsigned)hh < 64u) && ((unsigned)ww < 64u);
            int pp = (hh << 6) + ww;
            nb[idx] = pp;
            float l = 0.f;                 // OOB: k is zero-padded -> logit exactly 0
            if (ok) {
                vmask |= (1u << idx);
                const ushortT* kp = kbase + (size_t)pp * 32;
#pragma unroll
                for (int c = 0; c < 4; c++) {
                    ushort8v v = *(const ushort8v*)(kp + c * 8);
#pragma unroll
                    for (int j = 0; j < 8; j++) l += q[c * 8 + j] * bf2f(v[j]);
                }
                l *= ATT_SCALE;
            }
            lgt[idx] = l;
        }
    }

    float mx = lgt[0];
#pragma unroll
    for (int i = 1; i < 9; i++) mx = fmaxf(mx, lgt[i]);
    float e[9], s = 0.f;
#pragma unroll
    for (int i = 0; i < 9; i++) { e[i] = __expf(lgt[i] - mx); s += e[i]; }
    const float inv = 1.f / s;

    float acc[32];
#pragma unroll
    for (int d = 0; d < 32; d++) acc[d] = 0.f;
#pragma unroll
    for (int idx = 0; idx < 9; idx++) {
        if ((vmask >> idx) & 1u) {        // OOB: v = 0, contributes nothing (e[idx] stays in s)
            float pj = e[idx] * inv;
            const ushortT* vp = vbase + (size_t)nb[idx] * 32;
#pragma unroll
            for (int c = 0; c < 4; c++) {
                ushort8v v = *(const ushort8v*)(vp + c * 8);
#pragma unroll
                for (int j = 0; j < 8; j++) acc[c * 8 + j] += pj * bf2f(v[j]);
            }
        }
    }

#pragma unroll
    for (int c = 0; c < 4; c++) {         // overwrite own q slice
        ushort8v v;
#pragma unroll
        for (int j = 0; j < 8; j++) v[j] = f2bf(acc[c * 8 + j]);
        *(ushort8v*)(qp + c * 8) = v;
    }
}

// ---------------------------------------------------------------------------
extern "C" void kernel_launch(void* const* d_in, const int* in_sizes, int n_in,
                              void* d_out, int out_size, void* d_ws, size_t ws_size,
                              hipStream_t stream) {
    const float* x      = (const float*)d_in[0];  // (8,256,64,64) fp32
    const float* w_qkv  = (const float*)d_in[1];  // (768,256)
    const float* b_qkv  = (const float*)d_in[2];  // (768,)
    const float* w_proj = (const float*)d_in[3];  // (256,256)
    const float* b_proj = (const float*)d_in[4];  // (256,)

    // ws layout (256B-aligned): bqF | bpF | wqkvB | wprojB | qkv(head-major)
    char* ws = (char*)d_ws;
    float*   bqF    = (float*)(ws + 256);              // 768 f32
    float*   bpF    = (float*)(ws + 3328);             // 256 f32
    ushortT* wqkvB  = (ushortT*)(ws + 4352);           // 196608 bf16
    ushortT* wprojB = (ushortT*)(ws + 397568);         // 65536 bf16
    ushortT* qkv    = (ushortT*)(ws + 528640);         // 24 x 32768 x 32 bf16 = 48 MiB
    ushortT* xT     = (ushortT*)d_out;                 // (32768,256) bf16 scratch in d_out;
                                                       // fully overwritten by the final GEMM

    // 1) x (B,C,P) -> xT (B,P,C) bf16  +  folded param conversion
    transpose_cp<<<dim3(4, 64, 8), 256, 0, stream>>>(x, xT, w_qkv, w_proj, b_qkv, b_proj,
                                                     wqkvB, wprojB, bqF, bpF);

    // 2) qkv head-major = xT(32768,256) @ w_qkv^T + b_qkv   (bias along n)
    //    1536 blocks, XCD swizzle mode 0 (6 n-blocks per A-tile share an XCD)
    gemm_bt<<<dim3(1536), 256, 0, stream>>>(xT, wqkvB, 0, 256, 0,
                                            qkv, 0, 0, 1, 0,
                                            bqF, 0, 256, 0);

    // 3) attention in-place on head-major qkv (y overwrites q slices)
    attn_k<<<dim3(1024), 256, 0, stream>>>(qkv);

    // 4) out(b,256,4096) fp32 = w_proj @ y(b)^T + b_proj  (bias along m)
    //    512 blocks, XCD swizzle mode 1 (2 m-blocks per y-tile share an XCD)
    gemm_bt<<<dim3(512), 256, 0, stream>>>(wprojB, qkv, (long long)4096 * 32, 0, 1,
                                           d_out, (long long)256 * 4096, 4096, 0, 1,
                                           bpF, 1, 256, 1);
}